// Round 4
// baseline (254.697 us; speedup 1.0000x reference)
//
#include <hip/hip_runtime.h>
#include <hip/hip_bf16.h>

// Problem constants (fixed by the reference):
//   N=100000, E=500000, V=50000, NE=1000000, D=300, C=20, NG=512
#define NG 512
#define D_DIM 300
#define C_DIM 20
#define K3_EPB 2048
#define CH 256

// ---- GEMM tiling ----
#define BM 128        // M rows per block (512 = 4 tiles)
#define BN 304        // N padded from 300 (19 x 16)
#define KSTEP 32
#define KC 416        // K-chunk (13*32)
#define ASTRIDE 40    // LDS row stride in bf16 elems (80B: bank-spread, 16B-aligned)

typedef __attribute__((ext_vector_type(8))) short bf16x8;
typedef __attribute__((ext_vector_type(4))) float f32x4;

static __device__ inline ushort f2bf(float f) {
    union { float f; unsigned u; } x; x.f = f;
    unsigned r = x.u + 0x7FFF + ((x.u >> 16) & 1);   // RNE
    return (ushort)(r >> 16);
}

// ---------------- K1-min: in-degree ----------------
__global__ __launch_bounds__(256) void fb_count(const int* __restrict__ dst, int* __restrict__ cnt, int E) {
    for (int e = blockIdx.x * 256 + threadIdx.x; e < E; e += gridDim.x * 256)
        atomicAdd(&cnt[dst[e]], 1);
}

// ---------------- K2: scatter per-(graph,vocab) coefficients ----------------
__global__ __launch_bounds__(256) void coeff_scatter(const int* __restrict__ src,
                                                     const int* __restrict__ dst,
                                                     const int* __restrict__ eb,
                                                     const int* __restrict__ nodes_batch,
                                                     const float* __restrict__ edge_embed,
                                                     const int* __restrict__ graph_ids,
                                                     const int* __restrict__ cnt,
                                                     float* __restrict__ coeff,
                                                     int E, int K) {
    for (int e = blockIdx.x * 256 + threadIdx.x; e < E; e += gridDim.x * 256) {
        int d = dst[e];
        float s = edge_embed[eb[e]] / (float)max(cnt[d], 1);
        atomicAdd(&coeff[(size_t)graph_ids[d] * K + nodes_batch[src[e]]], s);
    }
}

// ---------------- K3: bf16 MFMA GEMM  gacc[512][300] += coeff[512][K] x B[K][300] ----------------
// grid decode: xcd=bid&7, mt=(bid>>3)&3, c=bid>>5; kch = c*8+xcd  (4 M-tiles of a
// K-chunk land on the same XCD -> B-chunk L2-resident). 8 waves, wave = 16 rows.
__global__ __launch_bounds__(512, 4) void gemm_kernel(const float* __restrict__ coeff,
                                                      const float* __restrict__ Bmat,
                                                      float* __restrict__ gacc,
                                                      int K, int nkch) {
    __shared__ __align__(16) ushort Al[BM * ASTRIDE];    // [row][k]
    __shared__ __align__(16) ushort Btl[BN * ASTRIDE];   // [n][k] (transposed B)
    int bid = blockIdx.x;
    int xcd = bid & 7;
    int mt = (bid >> 3) & 3;
    int c = bid >> 5;
    int kch = c * 8 + xcd;
    if (kch >= nkch) return;
    int M0 = mt * BM;
    int k0 = kch * KC;
    int kend = min(k0 + KC, K);

    int t = threadIdx.x;
    int wave = t >> 6, lane = t & 63;
    int lm = lane & 15, lk = lane >> 4;   // fragment coords

    f32x4 acc[19];
#pragma unroll
    for (int i = 0; i < 19; i++) acc[i] = (f32x4){0.f, 0.f, 0.f, 0.f};

    // staging roles
    int arow = t >> 2, apart = t & 3;         // A: 4 thr/row, 8 f32 each
    int bkk = t >> 4, bnb = t & 15;           // B: 16 thr/k-row

    for (int ks = k0; ks < kend; ks += KSTEP) {
        // ---- stage A (f32 -> bf16), rows M0..M0+127, k ks..ks+31
        {
            const float* srcp = coeff + (size_t)(M0 + arow) * K + ks + apart * 8;
            ushort v[8];
            if (ks + KSTEP <= K) {
                float4 f0 = *(const float4*)srcp;
                float4 f1 = *(const float4*)(srcp + 4);
                v[0] = f2bf(f0.x); v[1] = f2bf(f0.y); v[2] = f2bf(f0.z); v[3] = f2bf(f0.w);
                v[4] = f2bf(f1.x); v[5] = f2bf(f1.y); v[6] = f2bf(f1.z); v[7] = f2bf(f1.w);
            } else {
#pragma unroll
                for (int j = 0; j < 8; j++) {
                    int gk = ks + apart * 8 + j;
                    v[j] = (gk < K) ? f2bf(srcp[j]) : (ushort)0;
                }
            }
            int4 pk;
            pk.x = (int)v[0] | ((int)v[1] << 16);
            pk.y = (int)v[2] | ((int)v[3] << 16);
            pk.z = (int)v[4] | ((int)v[5] << 16);
            pk.w = (int)v[6] | ((int)v[7] << 16);
            *(int4*)&Al[arow * ASTRIDE + apart * 8] = pk;
        }
        // ---- stage B transposed (f32 -> bf16): Btl[n][k], k ks..ks+31, n 0..303
        {
            bool kok = (ks + bkk) < K;
            const float* brow = Bmat + (size_t)(ks + bkk) * D_DIM;
#pragma unroll
            for (int jj = 0; jj < 19; jj++) {
                int n = bnb + jj * 16;
                float f = (kok && n < D_DIM) ? brow[n] : 0.f;
                Btl[n * ASTRIDE + bkk] = f2bf(f);
            }
        }
        __syncthreads();
        // ---- MFMA: wave owns rows [wave*16, wave*16+16)
        bf16x8 af = *(const bf16x8*)&Al[(wave * 16 + lm) * ASTRIDE + lk * 8];
#pragma unroll
        for (int nf = 0; nf < 19; nf++) {
            bf16x8 bfr = *(const bf16x8*)&Btl[(nf * 16 + lm) * ASTRIDE + lk * 8];
            acc[nf] = __builtin_amdgcn_mfma_f32_16x16x32_bf16(af, bfr, acc[nf], 0, 0, 0);
        }
        __syncthreads();
    }
    // ---- epilogue: atomic accumulate partials (D: row=(l>>4)*4+r, col=l&15)
#pragma unroll
    for (int nf = 0; nf < 19; nf++) {
        int col = nf * 16 + lm;
        if (col < D_DIM) {
#pragma unroll
            for (int r = 0; r < 4; r++) {
                int row = M0 + wave * 16 + lk * 4 + r;
                atomicAdd(&gacc[row * D_DIM + col], acc[nf][r]);
            }
        }
    }
}

// ---------------- K4: per-graph ReLU + FC ----------------
__global__ __launch_bounds__(320) void fc_kernel(const float* __restrict__ gacc,
                                                 const float* __restrict__ fc_w,
                                                 const float* __restrict__ fc_b,
                                                 float* __restrict__ out) {
    __shared__ float wlds[D_DIM * C_DIM];
    __shared__ float accs[D_DIM];
    __shared__ float outs[C_DIM];
    int gid = blockIdx.x;
    int t = threadIdx.x;
    for (int i = t; i < D_DIM * C_DIM; i += 320) wlds[i] = fc_w[i];
    if (t < D_DIM) accs[t] = gacc[gid * D_DIM + t];
    if (t < C_DIM) outs[t] = fc_b[t];
    __syncthreads();
    if (t < C_DIM * 12) {
        int c = t % C_DIM;
        int ch = t / C_DIM;
        float p = 0.f;
#pragma unroll
        for (int d = ch * 25; d < ch * 25 + 25; d++) {
            float gv = accs[d];
            gv = gv > 0.f ? gv : 0.f;
            p += gv * wlds[d * C_DIM + c];
        }
        atomicAdd(&outs[c], p);
    }
    __syncthreads();
    if (t < C_DIM) out[gid * C_DIM + t] = outs[t];
}

// ================= fallback path (R3 structure) =================
__global__ __launch_bounds__(256) void count_kernel(const int* __restrict__ dst,
                                                    const int* __restrict__ graph_ids,
                                                    int* __restrict__ cnt,
                                                    int* __restrict__ gcnt, int E) {
    __shared__ int lg[NG];
    int t = threadIdx.x;
    for (int i = t; i < NG; i += 256) lg[i] = 0;
    __syncthreads();
    for (int e = blockIdx.x * 256 + t; e < E; e += gridDim.x * 256) {
        int d = dst[e];
        atomicAdd(&cnt[d], 1);
        atomicAdd(&lg[graph_ids[d]], 1);
    }
    __syncthreads();
    for (int i = t; i < NG; i += 256)
        if (lg[i]) atomicAdd(&gcnt[i], lg[i]);
}

__global__ __launch_bounds__(NG) void scan_kernel(const int* __restrict__ gcnt,
                                                  int* __restrict__ goff,
                                                  int* __restrict__ gfill) {
    __shared__ int s[NG];
    int t = threadIdx.x;
    int v = gcnt[t];
    s[t] = v;
    __syncthreads();
    for (int off = 1; off < NG; off <<= 1) {
        int x = (t >= off) ? s[t - off] : 0;
        __syncthreads();
        s[t] += x;
        __syncthreads();
    }
    int excl = s[t] - v;
    goff[t] = excl;
    gfill[t] = excl;
}

__global__ __launch_bounds__(256) void scatter_kernel(const int* __restrict__ src,
                                                      const int* __restrict__ dst,
                                                      const int* __restrict__ eb,
                                                      const int* __restrict__ nodes_batch,
                                                      const float* __restrict__ edge_embed,
                                                      const int* __restrict__ graph_ids,
                                                      const int* __restrict__ cnt,
                                                      int* __restrict__ gfill,
                                                      int2* __restrict__ elist, int E) {
    __shared__ int bcnt[NG];
    __shared__ int base[NG];
    int t = threadIdx.x;
    int e0 = blockIdx.x * K3_EPB;
    for (int i = t; i < NG; i += 256) bcnt[i] = 0;
    __syncthreads();
    int rows[K3_EPB / 256];
    float scales[K3_EPB / 256];
    int gids[K3_EPB / 256];
#pragma unroll
    for (int k = 0; k < K3_EPB / 256; k++) {
        int e = e0 + k * 256 + t;
        gids[k] = -1;
        if (e < E) {
            int d = dst[e];
            int g = graph_ids[d];
            gids[k] = g;
            rows[k] = nodes_batch[src[e]];
            scales[k] = edge_embed[eb[e]] / (float)max(cnt[d], 1);
            atomicAdd(&bcnt[g], 1);
        }
    }
    __syncthreads();
    for (int i = t; i < NG; i += 256) {
        int c2 = bcnt[i];
        base[i] = c2 ? atomicAdd(&gfill[i], c2) : 0;
        bcnt[i] = 0;
    }
    __syncthreads();
#pragma unroll
    for (int k = 0; k < K3_EPB / 256; k++) {
        int g = gids[k];
        if (g >= 0) {
            int pos = base[g] + atomicAdd(&bcnt[g], 1);
            elist[pos] = make_int2(rows[k], __float_as_int(scales[k]));
        }
    }
}

__global__ __launch_bounds__(320) void accum_kernel(const int2* __restrict__ elist,
                                                    const int* __restrict__ goff,
                                                    const float* __restrict__ node_embed,
                                                    float* __restrict__ gacc, int E) {
    __shared__ int2 tile[CH];
    __shared__ int goff_s[NG + 1];
    int t = threadIdx.x;
    int sub = t / 80;
    int lane = t % 80;
    int d0 = lane * 4;
    bool act = d0 < D_DIM;
    int pos0 = blockIdx.x * CH;
    int m = min(CH, E - pos0);
    for (int i = t; i < NG; i += 320) goff_s[i] = goff[i];
    if (t == 0) goff_s[NG] = E;
    for (int i = t; i < m; i += 320) tile[i] = elist[pos0 + i];
    __syncthreads();
    int lo = 0, hi = NG - 1;
    while (lo < hi) {
        int mid = (lo + hi + 1) >> 1;
        if (goff_s[mid] <= pos0) lo = mid; else hi = mid - 1;
    }
    int g = lo;
    int j = 0;
    while (j < m) {
        while (pos0 + j >= goff_s[g + 1]) g++;
        int end = min(m, goff_s[g + 1] - pos0);
        float ax = 0.f, ay = 0.f, az = 0.f, aw = 0.f;
        if (act) {
#pragma unroll 8
            for (int jj = j + sub; jj < end; jj += 4) {
                int2 pr = tile[jj];
                float s = __int_as_float(pr.y);
                const float4* rowp = (const float4*)(node_embed + (size_t)pr.x * D_DIM);
                float4 v = rowp[lane];
                ax += s * v.x; ay += s * v.y; az += s * v.z; aw += s * v.w;
            }
            float* dest = gacc + g * D_DIM + d0;
            atomicAdd(dest + 0, ax);
            atomicAdd(dest + 1, ay);
            atomicAdd(dest + 2, az);
            atomicAdd(dest + 3, aw);
        }
        j = end;
    }
}

extern "C" void kernel_launch(void* const* d_in, const int* in_sizes, int n_in,
                              void* d_out, int out_size, void* d_ws, size_t ws_size,
                              hipStream_t stream) {
    const int* nodes_batch = (const int*)d_in[0];
    const int* edges_batch = (const int*)d_in[1];
    const int* src = (const int*)d_in[2];
    const int* dst = (const int*)d_in[3];
    const int* graph_ids = (const int*)d_in[4];
    const float* node_embed = (const float*)d_in[5];
    const float* edge_embed = (const float*)d_in[6];
    const float* fc_w = (const float*)d_in[7];
    const float* fc_b = (const float*)d_in[8];
    float* out = (float*)d_out;

    int N = in_sizes[0];
    int E = in_sizes[2];
    int K = in_sizes[5] / D_DIM;   // vocab size V

    char* ws = (char*)d_ws;
    size_t off = 0;
    int* cnt = (int*)(ws + off); off += (size_t)N * 4;
    int* gcnt = (int*)(ws + off); off += NG * 4;
    int* goff = (int*)(ws + off); off += NG * 4;
    int* gfill = (int*)(ws + off); off += NG * 4;
    float* gacc = (float*)(ws + off); off += (size_t)NG * D_DIM * 4;
    off = (off + 15) & ~(size_t)15;
    size_t need_main = off + (size_t)NG * K * 4;
    size_t need_fb = off + (size_t)E * 8;

    if (ws_size >= need_main) {
        float* coeff = (float*)(ws + off);
        hipMemsetAsync(cnt, 0, (size_t)N * 4, stream);
        hipMemsetAsync(gacc, 0, (size_t)NG * D_DIM * 4, stream);
        hipMemsetAsync(coeff, 0, (size_t)NG * K * 4, stream);
        fb_count<<<256, 256, 0, stream>>>(dst, cnt, E);
        coeff_scatter<<<512, 256, 0, stream>>>(src, dst, edges_batch, nodes_batch,
                                               edge_embed, graph_ids, cnt, coeff, E, K);
        int nkch = (K + KC - 1) / KC;
        int grid = 32 * ((nkch + 7) / 8);
        gemm_kernel<<<grid, 512, 0, stream>>>(coeff, node_embed, gacc, K, nkch);
        fc_kernel<<<NG, 320, 0, stream>>>(gacc, fc_w, fc_b, out);
    } else if (ws_size >= need_fb) {
        int2* elist = (int2*)(ws + off);
        hipMemsetAsync(cnt, 0, (size_t)N * 4, stream);
        hipMemsetAsync(gcnt, 0, NG * 4, stream);
        hipMemsetAsync(gacc, 0, (size_t)NG * D_DIM * 4, stream);
        count_kernel<<<256, 256, 0, stream>>>(dst, graph_ids, cnt, gcnt, E);
        scan_kernel<<<1, NG, 0, stream>>>(gcnt, goff, gfill);
        int nsb = (E + K3_EPB - 1) / K3_EPB;
        scatter_kernel<<<nsb, 256, 0, stream>>>(src, dst, edges_batch, nodes_batch, edge_embed,
                                                graph_ids, cnt, gfill, elist, E);
        int nab = (E + CH - 1) / CH;
        accum_kernel<<<nab, 320, 0, stream>>>(elist, goff, node_embed, gacc, E);
        fc_kernel<<<NG, 320, 0, stream>>>(gacc, fc_w, fc_b, out);
    }
}